// Round 1
// baseline (17.384 us; speedup 1.0000x reference)
//
#include <hip/hip_runtime.h>

// Problem constants (B=128 states, n=16 qubits, D=2^16 amplitudes).
#define BATCH 128
#define DIM 65536
#define HALF 32768
#define CHUNKS 8
#define CHUNK_PAIRS (HALF / CHUNKS)   // 4096 pairs per block
#define TPB 256                       // 16 floats/thread/array = 4x float4

// Math: out[b] = cos^2(t)*sum(|a|^2-|b|^2) - 2 sin(t)*Re<a,b> + 2 sin(t)cos(t)*Im<a,b>
// where t = thetas[0], a = first half (bit0=0), b = second half (bit0=1).
// CNOT ladder commutes with Z_0; unitary gates on qubits 1..15 cancel.

__global__ __launch_bounds__(TPB) void qcirc_partial(
    const float* __restrict__ re, const float* __restrict__ im,
    float* __restrict__ ws)
{
    const int b = blockIdx.y;
    const int chunk = blockIdx.x;
    const int t = threadIdx.x;

    const float* ra_p = re + (size_t)b * DIM;        // re, bit0 = 0 half
    const float* rb_p = ra_p + HALF;                 // re, bit0 = 1 half
    const float* ia_p = im + (size_t)b * DIM;        // im, bit0 = 0 half
    const float* ib_p = ia_p + HALF;                 // im, bit0 = 1 half

    const int base = chunk * CHUNK_PAIRS;

    float diff = 0.f;   // sum |a|^2 - |b|^2
    float dre  = 0.f;   // Re sum conj(a)*b
    float dim_ = 0.f;   // Im sum conj(a)*b

    #pragma unroll
    for (int i = 0; i < 4; ++i) {
        const int r = base + (i * TPB + t) * 4;      // coalesced float4
        const float4 ra = *reinterpret_cast<const float4*>(ra_p + r);
        const float4 ia = *reinterpret_cast<const float4*>(ia_p + r);
        const float4 rb = *reinterpret_cast<const float4*>(rb_p + r);
        const float4 ib = *reinterpret_cast<const float4*>(ib_p + r);

        diff += ra.x*ra.x + ia.x*ia.x - rb.x*rb.x - ib.x*ib.x;
        diff += ra.y*ra.y + ia.y*ia.y - rb.y*rb.y - ib.y*ib.y;
        diff += ra.z*ra.z + ia.z*ia.z - rb.z*rb.z - ib.z*ib.z;
        diff += ra.w*ra.w + ia.w*ia.w - rb.w*rb.w - ib.w*ib.w;

        dre  += ra.x*rb.x + ia.x*ib.x;
        dre  += ra.y*rb.y + ia.y*ib.y;
        dre  += ra.z*rb.z + ia.z*ib.z;
        dre  += ra.w*rb.w + ia.w*ib.w;

        dim_ += ra.x*ib.x - ia.x*rb.x;
        dim_ += ra.y*ib.y - ia.y*rb.y;
        dim_ += ra.z*ib.z - ia.z*rb.z;
        dim_ += ra.w*ib.w - ia.w*rb.w;
    }

    // wave64 butterfly reduce
    #pragma unroll
    for (int off = 32; off > 0; off >>= 1) {
        diff += __shfl_down(diff, off);
        dre  += __shfl_down(dre,  off);
        dim_ += __shfl_down(dim_, off);
    }

    __shared__ float sdata[3][TPB / 64];
    const int wave = t >> 6, lane = t & 63;
    if (lane == 0) {
        sdata[0][wave] = diff;
        sdata[1][wave] = dre;
        sdata[2][wave] = dim_;
    }
    __syncthreads();
    if (t == 0) {
        float d = 0.f, r = 0.f, ii = 0.f;
        #pragma unroll
        for (int w = 0; w < TPB / 64; ++w) {
            d += sdata[0][w]; r += sdata[1][w]; ii += sdata[2][w];
        }
        float* o = ws + ((size_t)b * CHUNKS + chunk) * 3;
        o[0] = d; o[1] = r; o[2] = ii;
    }
}

__global__ __launch_bounds__(128) void qcirc_final(
    const float* __restrict__ ws, const float* __restrict__ thetas,
    float* __restrict__ out)
{
    const int b = blockIdx.x * blockDim.x + threadIdx.x;
    if (b >= BATCH) return;

    const float theta = thetas[0];
    const float ct = cosf(theta);
    const float st = sinf(theta);

    float d = 0.f, r = 0.f, ii = 0.f;
    #pragma unroll
    for (int c = 0; c < CHUNKS; ++c) {
        const float* o = ws + ((size_t)b * CHUNKS + c) * 3;
        d += o[0]; r += o[1]; ii += o[2];
    }
    out[b] = ct * ct * d - 2.f * st * r + 2.f * st * ct * ii;
}

extern "C" void kernel_launch(void* const* d_in, const int* in_sizes, int n_in,
                              void* d_out, int out_size, void* d_ws, size_t ws_size,
                              hipStream_t stream) {
    const float* re     = (const float*)d_in[0];
    const float* im     = (const float*)d_in[1];
    const float* thetas = (const float*)d_in[2];
    float* out = (float*)d_out;
    float* ws  = (float*)d_ws;   // needs 128*8*3*4 = 12 KiB

    dim3 grid(CHUNKS, BATCH);
    qcirc_partial<<<grid, TPB, 0, stream>>>(re, im, ws);
    qcirc_final<<<1, 128, 0, stream>>>(ws, thetas, out);
}